// Round 3
// baseline (493.053 us; speedup 1.0000x reference)
//
#include <hip/hip_runtime.h>

#define BATCH 8
#define NPOS 784          // H*W per batch
#define CH 512
#define DI 4096
#define PPC 4             // positions per chunk
#define CHUNKS (NPOS / PPC)   // 196
#define PHI_LEN 8705      // 1 + 512 + 2*4096
#define S_FLOATS (BATCH * 2 * 2049 * 2)
#define PHI_OFF S_FLOATS

__device__ __forceinline__ float2 cmul(float2 a, float2 b) {
  return make_float2(a.x * b.x - a.y * b.y, a.x * b.y + a.y * b.x);
}

// forward DFT4 (w4 = -i)
__device__ __forceinline__ void dft4(float2& a, float2& b, float2& c, float2& d) {
  float t0x = a.x + c.x, t0y = a.y + c.y;
  float t1x = a.x - c.x, t1y = a.y - c.y;
  float t2x = b.x + d.x, t2y = b.y + d.y;
  float t3x = b.x - d.x, t3y = b.y - d.y;
  a = make_float2(t0x + t2x, t0y + t2y);
  c = make_float2(t0x - t2x, t0y - t2y);
  b = make_float2(t1x + t3y, t1y - t3x);   // t1 - i*t3
  d = make_float2(t1x - t3y, t1y + t3x);   // t1 + i*t3
}

// forward 16-point DFT, natural time order in.
// On exit slot (k1 + 4*k2) holds bin (k2 + 4*k1).
__device__ __forceinline__ void dft16(float2 v[16]) {
  dft4(v[0], v[4], v[8], v[12]);
  dft4(v[1], v[5], v[9], v[13]);
  dft4(v[2], v[6], v[10], v[14]);
  dft4(v[3], v[7], v[11], v[15]);
  const float C1 = 0.92387953251128674f, S1 = 0.38268343236508977f;
  const float R = 0.70710678118654752f;
  v[5]  = cmul(v[5],  make_float2( C1, -S1));
  v[9]  = cmul(v[9],  make_float2(  R,  -R));
  v[13] = cmul(v[13], make_float2( S1, -C1));
  v[6]  = cmul(v[6],  make_float2(  R,  -R));
  v[10] = cmul(v[10], make_float2(0.f, -1.f));
  v[14] = cmul(v[14], make_float2( -R,  -R));
  v[7]  = cmul(v[7],  make_float2( S1, -C1));
  v[11] = cmul(v[11], make_float2( -R,  -R));
  v[15] = cmul(v[15], make_float2(-C1,  S1));
  dft4(v[0], v[1], v[2], v[3]);
  dft4(v[4], v[5], v[6], v[7]);
  dft4(v[8], v[9], v[10], v[11]);
  dft4(v[12], v[13], v[14], v[15]);
}

// v[u] *= w^u with low register pressure (base set w,w2,w3,w4,w8,w12)
__device__ __forceinline__ void twiddle16(float2 v[16], float2 w) {
  float2 w2 = cmul(w, w);
  float2 w3 = cmul(w2, w);
  float2 w4 = cmul(w2, w2);
  float2 w8 = cmul(w4, w4);
  float2 w12 = cmul(w8, w4);
  v[1] = cmul(v[1], w);
  v[2] = cmul(v[2], w2);
  v[3] = cmul(v[3], w3);
  v[4] = cmul(v[4], w4);
  v[5] = cmul(v[5], cmul(w4, w));
  v[6] = cmul(v[6], cmul(w4, w2));
  v[7] = cmul(v[7], cmul(w4, w3));
  v[8] = cmul(v[8], w8);
  v[9] = cmul(v[9], cmul(w8, w));
  v[10] = cmul(v[10], cmul(w8, w2));
  v[11] = cmul(v[11], cmul(w8, w3));
  v[12] = cmul(v[12], w12);
  v[13] = cmul(v[13], cmul(w12, w));
  v[14] = cmul(v[14], cmul(w12, w2));
  v[15] = cmul(v[15], cmul(w12, w3));
}

// 4096-pt forward FFT, radix-16^3, input scattered digit-reversed+swizzled,
// output natural order at phys(i) = i ^ ((i>>4)&15).
__device__ __forceinline__ void fft_stages(float2* Z, int tid, float2 w1b,
                                           float2 w2b) {
  const int tl = tid & 15;
  const int g16 = tid << 4;
  const int b1 = (tid >> 4) << 8;
  const int base2 = (tid & 240) | (tl ^ ((tid >> 4) & 15));
  __syncthreads();  // scatter done
  {  // stage 0: contiguous 16-blocks, twiddle-free
    float2 v[16];
    #pragma unroll
    for (int u = 0; u < 16; ++u) v[u] = Z[g16 + (u ^ tl)];
    dft16(v);
    #pragma unroll
    for (int k = 0; k < 16; ++k)
      Z[g16 + (k ^ tl)] = v[(k >> 2) + ((k & 3) << 2)];
  }
  __syncthreads();
  {  // stage 1: stride 16 within 256-blocks
    float2 v[16];
    #pragma unroll
    for (int u = 0; u < 16; ++u) v[u] = Z[b1 + (u << 4) + (tl ^ u)];
    twiddle16(v, w1b);
    dft16(v);
    #pragma unroll
    for (int k = 0; k < 16; ++k)
      Z[b1 + (k << 4) + (tl ^ k)] = v[(k >> 2) + ((k & 3) << 2)];
  }
  __syncthreads();
  {  // stage 2: stride 256
    float2 v[16];
    #pragma unroll
    for (int u = 0; u < 16; ++u) v[u] = Z[(u << 8) + base2];
    twiddle16(v, w2b);
    dft16(v);
    #pragma unroll
    for (int k = 0; k < 16; ++k)
      Z[(k << 8) + base2] = v[(k >> 2) + ((k & 3) << 2)];
  }
  __syncthreads();
}

__global__ __launch_bounds__(256, 4) void cbp_stage1(
    const float* __restrict__ x, const float* __restrict__ alpha,
    const int* __restrict__ h_idx, const int* __restrict__ s_bits,
    float* __restrict__ ws) {
  __shared__ float2 Z[DI];
  float* Zf = (float*)Z;
  const int tid = threadIdx.x;
  const int bb = blockIdx.x / CHUNKS;
  const int ch = blockIdx.x % CHUNKS;

  // hash -> phys(digitrev16(h)), sign packed in top bit (set == flip)
  auto mapq = [](int h, int s) {
    int r = ((h & 15) << 8) | (h & 240) | (h >> 8);
    return (r ^ ((r >> 4) & 15)) | ((s ^ 1) << 31);
  };
  auto sgn = [](float v, int p) {
    return __int_as_float(__float_as_int(v) ^ (p & 0x80000000u));
  };
  const int c0 = tid * 2, c1 = c0 + 1;
  const int q0a = mapq(h_idx[c0], s_bits[c0]);
  const int q0b = mapq(h_idx[c1], s_bits[c1]);
  const int q1a = mapq(h_idx[CH + c0], s_bits[CH + c0]);
  const int q1b = mapq(h_idx[CH + c1], s_bits[CH + c1]);
  const int q2a = mapq(h_idx[2 * CH + c0], s_bits[2 * CH + c0]);
  const int q2b = mapq(h_idx[2 * CH + c1], s_bits[2 * CH + c1]);

  const int tl = tid & 15;
  const int base2 = (tid & 240) | (tl ^ ((tid >> 4) & 15));
  float sv_, cv_;
  __sincosf(-2.4543692606170259e-2f * (float)tl, &sv_, &cv_);   // -2pi/256*j
  const float2 w1b = make_float2(cv_, sv_);
  __sincosf(-1.5339807878856412e-3f * (float)tid, &sv_, &cv_);  // -2pi/4096*t
  const float2 w2b = make_float2(cv_, sv_);

  float2 acc2[8], acc3[8], carry[8];
  #pragma unroll
  for (int j = 0; j < 8; ++j) {
    acc2[j] = make_float2(0.f, 0.f);
    acc3[j] = make_float2(0.f, 0.f);
  }
  float acc2x = 0.f, acc3x = 0.f, carryx = 0.f;
  float xsa = 0.f, xsb = 0.f;

  #pragma unroll
  for (int q = 0; q < 16; ++q) Z[tid + (q << 8)] = make_float2(0.f, 0.f);
  __syncthreads();

  for (int ip = 0; ip < PPC / 2; ++ip) {
    const int n0 = bb * NPOS + ch * PPC + ip * 2;
    const float2 xv0 = *(const float2*)(x + (size_t)n0 * CH + c0);
    const float2 xv1 = *(const float2*)(x + (size_t)(n0 + 1) * CH + c0);
    xsa += xv0.x + xv1.x;
    xsb += xv0.y + xv1.y;

    // ---- FFT1: sk0(n) + i*sk1(n) ----
    atomicAdd(&Zf[2 * (q0a & 0xFFF)], sgn(xv0.x, q0a));
    atomicAdd(&Zf[2 * (q0b & 0xFFF)], sgn(xv0.y, q0b));
    atomicAdd(&Zf[2 * (q1a & 0xFFF) + 1], sgn(xv0.x, q1a));
    atomicAdd(&Zf[2 * (q1b & 0xFFF) + 1], sgn(xv0.y, q1b));
    fft_stages(Z, tid, w1b, w2b);
    #pragma unroll
    for (int jj = 0; jj < 8; ++jj) {
      const int k = tid + (jj << 8);
      const int ak = (jj << 8) + base2;
      const int m = (DI - k) & (DI - 1);
      const int am = m ^ ((m >> 4) & 15);
      float2 Zk = Z[ak], Zm = Z[am];
      Z[ak] = make_float2(0.f, 0.f);
      Z[am] = make_float2(0.f, 0.f);
      float2 E = make_float2(0.5f * (Zk.x + Zm.x), 0.5f * (Zk.y - Zm.y));
      float2 O = make_float2(0.5f * (Zk.y + Zm.y), -0.5f * (Zk.x - Zm.x));
      float2 P = cmul(E, O);          // P2(n)
      carry[jj] = P;
      acc2[jj].x += P.x;
      acc2[jj].y += P.y;
    }
    if (tid == 0) {
      float2 Zq = Z[2048];
      Z[2048] = make_float2(0.f, 0.f);
      carryx = Zq.x * Zq.y;
      acc2x += carryx;
    }
    __syncthreads();

    // ---- FFT2: sk2(n) + i*sk0(n+1) ----
    atomicAdd(&Zf[2 * (q2a & 0xFFF)], sgn(xv0.x, q2a));
    atomicAdd(&Zf[2 * (q2b & 0xFFF)], sgn(xv0.y, q2b));
    atomicAdd(&Zf[2 * (q0a & 0xFFF) + 1], sgn(xv1.x, q0a));
    atomicAdd(&Zf[2 * (q0b & 0xFFF) + 1], sgn(xv1.y, q0b));
    fft_stages(Z, tid, w1b, w2b);
    #pragma unroll
    for (int jj = 0; jj < 8; ++jj) {
      const int k = tid + (jj << 8);
      const int ak = (jj << 8) + base2;
      const int m = (DI - k) & (DI - 1);
      const int am = m ^ ((m >> 4) & 15);
      float2 Zk = Z[ak], Zm = Z[am];
      Z[ak] = make_float2(0.f, 0.f);
      Z[am] = make_float2(0.f, 0.f);
      float2 E = make_float2(0.5f * (Zk.x + Zm.x), 0.5f * (Zk.y - Zm.y));  // X2(n)
      float2 O = make_float2(0.5f * (Zk.y + Zm.y), -0.5f * (Zk.x - Zm.x)); // X0(n+1)
      float2 P3 = cmul(carry[jj], E);
      acc3[jj].x += P3.x;
      acc3[jj].y += P3.y;
      carry[jj] = O;
    }
    if (tid == 0) {
      float2 Zq = Z[2048];
      Z[2048] = make_float2(0.f, 0.f);
      acc3x += carryx * Zq.x;
      carryx = Zq.y;
    }
    __syncthreads();

    // ---- FFT3: sk1(n+1) + i*sk2(n+1) ----
    atomicAdd(&Zf[2 * (q1a & 0xFFF)], sgn(xv1.x, q1a));
    atomicAdd(&Zf[2 * (q1b & 0xFFF)], sgn(xv1.y, q1b));
    atomicAdd(&Zf[2 * (q2a & 0xFFF) + 1], sgn(xv1.x, q2a));
    atomicAdd(&Zf[2 * (q2b & 0xFFF) + 1], sgn(xv1.y, q2b));
    fft_stages(Z, tid, w1b, w2b);
    #pragma unroll
    for (int jj = 0; jj < 8; ++jj) {
      const int k = tid + (jj << 8);
      const int ak = (jj << 8) + base2;
      const int m = (DI - k) & (DI - 1);
      const int am = m ^ ((m >> 4) & 15);
      float2 Zk = Z[ak], Zm = Z[am];
      Z[ak] = make_float2(0.f, 0.f);
      Z[am] = make_float2(0.f, 0.f);
      float2 E = make_float2(0.5f * (Zk.x + Zm.x), 0.5f * (Zk.y - Zm.y));  // X1(n+1)
      float2 O = make_float2(0.5f * (Zk.y + Zm.y), -0.5f * (Zk.x - Zm.x)); // X2(n+1)
      float2 P = cmul(carry[jj], E);  // P2(n+1)
      acc2[jj].x += P.x;
      acc2[jj].y += P.y;
      float2 P3 = cmul(P, O);
      acc3[jj].x += P3.x;
      acc3[jj].y += P3.y;
    }
    if (tid == 0) {
      float2 Zq = Z[2048];
      Z[2048] = make_float2(0.f, 0.f);
      float t = carryx * Zq.x;
      acc2x += t;
      acc3x += t * Zq.y;
    }
    __syncthreads();
  }

  // ---- writeback ----
  float* S = ws;
  #pragma unroll
  for (int jj = 0; jj < 8; ++jj) {
    const int k = tid + (jj << 8);
    float* p2p = S + ((size_t)(bb * 2 + 0) * 2049 + k) * 2;
    atomicAdd(p2p, acc2[jj].x);
    atomicAdd(p2p + 1, acc2[jj].y);
    float* p3p = S + ((size_t)(bb * 2 + 1) * 2049 + k) * 2;
    atomicAdd(p3p, acc3[jj].x);
    atomicAdd(p3p + 1, acc3[jj].y);
  }
  if (tid == 0) {
    atomicAdd(S + ((size_t)(bb * 2 + 0) * 2049 + 2048) * 2, acc2x);
    atomicAdd(S + ((size_t)(bb * 2 + 1) * 2049 + 2048) * 2, acc3x);
  }

  const float sc1 = alpha[1] * (1.0f / (float)NPOS);
  float* phi = ws + PHI_OFF;
  atomicAdd(&phi[(size_t)bb * PHI_LEN + 1 + c0], xsa * sc1);
  atomicAdd(&phi[(size_t)bb * PHI_LEN + 1 + c1], xsb * sc1);
}

// ---------------- stage 2 (radix-2 FFT, 16 blocks, negligible) -------------
__device__ inline void fft4096_r2(float2* Z, const float2* W, int tid) {
  for (int s = 1; s <= 12; ++s) {
    __syncthreads();
    const int half = 1 << (s - 1);
    const int tsh = 12 - s;
    #pragma unroll
    for (int q = 0; q < 8; ++q) {
      int bidx = tid + q * 256;
      int j = bidx & (half - 1);
      int i1 = ((bidx >> (s - 1)) << s) + j;
      int i2 = i1 + half;
      float2 w = W[j << tsh];
      float2 u = Z[i1];
      float2 v = Z[i2];
      float2 t = cmul(w, v);
      Z[i1] = make_float2(u.x + t.x, u.y + t.y);
      Z[i2] = make_float2(u.x - t.x, u.y - t.y);
    }
  }
  __syncthreads();
}

__global__ __launch_bounds__(256) void cbp_stage2(
    const float* __restrict__ ws_in, const float* __restrict__ alpha,
    float* __restrict__ ws_phi) {
  __shared__ float2 Z[DI];
  __shared__ float2 W[DI / 2];
  const int tid = threadIdx.x;

  for (int r = tid; r < DI / 2; r += 256) {
    float ang = 1.5339807878856412e-3f * (float)r;  // +2pi/4096*r (inverse)
    float sv, cv;
    sincosf(ang, &sv, &cv);
    W[r] = make_float2(cv, sv);
  }

  const int b = blockIdx.x >> 1;
  const int t = blockIdx.x & 1;
  const float* Sp = ws_in + (size_t)(b * 2 + t) * 2049 * 2;

  for (int k = tid; k <= 2048; k += 256) {
    float re = Sp[k * 2];
    float im = Sp[k * 2 + 1];
    Z[__brev((unsigned)k) >> 20] = make_float2(re, im);
    if (k > 0 && k < 2048) {
      Z[__brev((unsigned)(DI - k)) >> 20] = make_float2(re, -im);
    }
  }
  fft4096_r2(Z, W, tid);

  const float scale = alpha[2 + t] / ((float)DI * (float)NPOS);
  float* out = ws_phi + (size_t)b * PHI_LEN + 513 + t * DI;
  for (int d = tid; d < DI; d += 256) out[d] = Z[d].x * scale;
}

__global__ __launch_bounds__(256) void cbp_stage3(
    const float* __restrict__ ws_phi, const float* __restrict__ alpha,
    float* __restrict__ out) {
  __shared__ float red[4];
  const int b = blockIdx.x;
  const int tid = threadIdx.x;
  const float* pr = ws_phi + (size_t)b * PHI_LEN;
  const float a0 = alpha[0];

  float w[35];
  float ssum = 0.f;
  #pragma unroll
  for (int j = 0; j < 35; ++j) {
    const int idx = tid + j * 256;
    float wv = 0.f;
    if (idx < PHI_LEN) {
      float v = (idx == 0) ? a0 : pr[idx];
      float sq = sqrtf(fabsf(v) + 1e-12f);
      wv = (v > 0.f) ? sq : ((v < 0.f) ? -sq : 0.f);
    }
    w[j] = wv;
    ssum += wv * wv;
  }
  for (int off = 32; off > 0; off >>= 1) ssum += __shfl_down(ssum, off);
  if ((tid & 63) == 0) red[tid >> 6] = ssum;
  __syncthreads();
  const float tot = red[0] + red[1] + red[2] + red[3];
  const float inv = 1.0f / sqrtf(tot);

  #pragma unroll
  for (int j = 0; j < 35; ++j) {
    const int idx = tid + j * 256;
    if (idx < PHI_LEN) out[(size_t)b * PHI_LEN + idx] = w[j] * inv;
  }
}

extern "C" void kernel_launch(void* const* d_in, const int* in_sizes, int n_in,
                              void* d_out, int out_size, void* d_ws,
                              size_t ws_size, hipStream_t stream) {
  const float* x = (const float*)d_in[0];
  const float* alpha = (const float*)d_in[1];
  const int* h_idx = (const int*)d_in[2];
  const int* s_bits = (const int*)d_in[3];
  float* out = (float*)d_out;
  float* ws = (float*)d_ws;

  const size_t zero_bytes = (size_t)(S_FLOATS + BATCH * PHI_LEN) * sizeof(float);
  hipMemsetAsync(d_ws, 0, zero_bytes, stream);

  cbp_stage1<<<dim3(BATCH * CHUNKS), dim3(256), 0, stream>>>(x, alpha, h_idx,
                                                             s_bits, ws);
  cbp_stage2<<<dim3(BATCH * 2), dim3(256), 0, stream>>>(ws, alpha,
                                                        ws + PHI_OFF);
  cbp_stage3<<<dim3(BATCH), dim3(256), 0, stream>>>(ws + PHI_OFF, alpha, out);
}

// Round 4
// 210.465 us; speedup vs baseline: 2.3427x; 2.3427x over previous
//
#include <hip/hip_runtime.h>

#define BATCH 8
#define NPOS 784          // H*W per batch
#define CH 512
#define DI 4096
#define PPC 14            // positions per chunk (even, NPOS/PPC integral)
#define CHUNKS (NPOS / PPC)   // 56
#define PHI_LEN 8705      // 1 + 512 + 2*4096
#define S_FLOATS (BATCH * 2 * 2049 * 2)
#define PHI_OFF S_FLOATS

__device__ __forceinline__ float2 cmul(float2 a, float2 b) {
  return make_float2(a.x * b.x - a.y * b.y, a.x * b.y + a.y * b.x);
}
__device__ __forceinline__ float2 f2add(float2 a, float2 b) {
  return make_float2(a.x + b.x, a.y + b.y);
}
__device__ __forceinline__ float2 f2sub(float2 a, float2 b) {
  return make_float2(a.x - b.x, a.y - b.y);
}

// forward DFT4 (w4 = -i), natural order out
__device__ __forceinline__ void dft4(float2& a, float2& b, float2& c, float2& d) {
  float t0x = a.x + c.x, t0y = a.y + c.y;
  float t1x = a.x - c.x, t1y = a.y - c.y;
  float t2x = b.x + d.x, t2y = b.y + d.y;
  float t3x = b.x - d.x, t3y = b.y - d.y;
  a = make_float2(t0x + t2x, t0y + t2y);
  c = make_float2(t0x - t2x, t0y - t2y);
  b = make_float2(t1x + t3y, t1y - t3x);   // t1 - i*t3
  d = make_float2(t1x - t3y, t1y + t3x);   // t1 + i*t3
}

// forward 8-point DFT, natural in, natural out (v[0..7])
__device__ __forceinline__ void dft8(float2 v[8]) {
  float2 e0 = v[0], e1 = v[2], e2 = v[4], e3 = v[6];
  dft4(e0, e1, e2, e3);
  float2 o0 = v[1], o1 = v[3], o2 = v[5], o3 = v[7];
  dft4(o0, o1, o2, o3);
  const float r = 0.70710678118654752f;
  o1 = make_float2(r * (o1.x + o1.y), r * (o1.y - o1.x));   // *w8^1
  o2 = make_float2(o2.y, -o2.x);                            // *-i
  o3 = make_float2(r * (o3.y - o3.x), -r * (o3.x + o3.y));  // *w8^3
  v[0] = f2add(e0, o0); v[4] = f2sub(e0, o0);
  v[1] = f2add(e1, o1); v[5] = f2sub(e1, o1);
  v[2] = f2add(e2, o2); v[6] = f2sub(e2, o2);
  v[3] = f2add(e3, o3); v[7] = f2sub(e3, o3);
}

// v[u] *= w^u, u=0..7
__device__ __forceinline__ void twiddle8(float2 v[8], float2 w) {
  float2 w2 = cmul(w, w);
  float2 w3 = cmul(w2, w);
  float2 w4 = cmul(w2, w2);
  v[1] = cmul(v[1], w);
  v[2] = cmul(v[2], w2);
  v[3] = cmul(v[3], w3);
  v[4] = cmul(v[4], w4);
  v[5] = cmul(v[5], cmul(w4, w));
  v[6] = cmul(v[6], cmul(w4, w2));
  v[7] = cmul(v[7], cmul(w4, w3));
}

// 4096-pt forward FFT, radix-8^4, 512 threads. Input scattered at
// phys(digitrev8(n)); output natural order at phys(i) = i ^ ((i>>4)&15).
__device__ __forceinline__ void fft_stages8(float2* Z, int t, float2 w1b,
                                            float2 w2b, float2 w3b) {
  __syncthreads();  // scatter done
  {  // stage 0: contiguous 8-blocks, twiddle-free
    const int base = t << 3;
    const int mask0 = (t >> 1) & 15;
    float2 v[8];
    #pragma unroll
    for (int u = 0; u < 8; ++u) v[u] = Z[(base + u) ^ mask0];
    dft8(v);
    #pragma unroll
    for (int k = 0; k < 8; ++k) Z[(base + k) ^ mask0] = v[k];
  }
  __syncthreads();
  {  // stage 1: groups of 64, stride 8, twiddle w64^{j*u}
    const int base = ((t >> 3) << 6) + (t & 7);
    const int g4 = (t >> 3) << 2;
    float2 v[8];
    #pragma unroll
    for (int u = 0; u < 8; ++u)
      v[u] = Z[(base + (u << 3)) ^ ((g4 + (u >> 1)) & 15)];
    twiddle8(v, w1b);
    dft8(v);
    #pragma unroll
    for (int k = 0; k < 8; ++k)
      Z[(base + (k << 3)) ^ ((g4 + (k >> 1)) & 15)] = v[k];
  }
  __syncthreads();
  {  // stage 2: groups of 512, stride 64, twiddle w512^{j*u}
    const int base = ((t >> 6) << 9) + (t & 63);
    const int jh = (t & 63) >> 4;
    float2 v[8];
    #pragma unroll
    for (int u = 0; u < 8; ++u)
      v[u] = Z[(base + (u << 6)) ^ (((u << 2) + jh) & 15)];
    twiddle8(v, w2b);
    dft8(v);
    #pragma unroll
    for (int k = 0; k < 8; ++k)
      Z[(base + (k << 6)) ^ (((k << 2) + jh) & 15)] = v[k];
  }
  __syncthreads();
  {  // stage 3: stride 512, twiddle w4096^{t*u}
    const int mask3 = (t >> 4) & 15;
    float2 v[8];
    #pragma unroll
    for (int u = 0; u < 8; ++u) v[u] = Z[(t + (u << 9)) ^ mask3];
    twiddle8(v, w3b);
    dft8(v);
    #pragma unroll
    for (int k = 0; k < 8; ++k) Z[(t + (k << 9)) ^ mask3] = v[k];
  }
  __syncthreads();
}

__global__ __launch_bounds__(512) void cbp_stage1(
    const float* __restrict__ x, const float* __restrict__ alpha,
    const int* __restrict__ h_idx, const int* __restrict__ s_bits,
    float* __restrict__ ws) {
  __shared__ float2 Z[DI];
  float* Zf = (float*)Z;
  const int t = threadIdx.x;
  const int bb = blockIdx.x / CHUNKS;
  const int ch = blockIdx.x % CHUNKS;

  // hash -> phys(digitrev8(h)); sign packed in top bit (set == flip)
  auto mapq = [](int h, int s) {
    int r = ((h & 7) << 9) | (((h >> 3) & 7) << 6) | (((h >> 6) & 7) << 3) |
            (h >> 9);
    return (r ^ ((r >> 4) & 15)) | ((s ^ 1) << 31);
  };
  auto sgn = [](float v, int p) {
    return __int_as_float(__float_as_int(v) ^ ((unsigned)p & 0x80000000u));
  };
  const int q0 = mapq(h_idx[t], s_bits[t]);
  const int q1 = mapq(h_idx[CH + t], s_bits[CH + t]);
  const int q2 = mapq(h_idx[2 * CH + t], s_bits[2 * CH + t]);

  float sv_, cv_;
  __sincosf(-9.8174770424681038e-2f * (float)(t & 7), &sv_, &cv_);   // -2pi/64*j
  const float2 w1b = make_float2(cv_, sv_);
  __sincosf(-1.2271846303085130e-2f * (float)(t & 63), &sv_, &cv_);  // -2pi/512*j
  const float2 w2b = make_float2(cv_, sv_);
  __sincosf(-1.5339807878856412e-3f * (float)t, &sv_, &cv_);         // -2pi/4096*t
  const float2 w3b = make_float2(cv_, sv_);

  const int mask3 = (t >> 4) & 15;

  float2 acc2[4], acc3[4], carry[4];
  #pragma unroll
  for (int j = 0; j < 4; ++j) {
    acc2[j] = make_float2(0.f, 0.f);
    acc3[j] = make_float2(0.f, 0.f);
  }
  float acc2x = 0.f, acc3x = 0.f, carryx = 0.f;
  float xs = 0.f;

  #pragma unroll
  for (int q = 0; q < 8; ++q) Z[t + (q << 9)] = make_float2(0.f, 0.f);
  __syncthreads();

  for (int ip = 0; ip < PPC / 2; ++ip) {
    const int n0 = bb * NPOS + ch * PPC + ip * 2;
    const float xv0 = x[(size_t)n0 * CH + t];
    const float xv1 = x[(size_t)(n0 + 1) * CH + t];
    xs += xv0 + xv1;

    // ---- FFT1: sk0(n) + i*sk1(n) ----
    atomicAdd(&Zf[2 * (q0 & 0xFFF)], sgn(xv0, q0));
    atomicAdd(&Zf[2 * (q1 & 0xFFF) + 1], sgn(xv0, q1));
    fft_stages8(Z, t, w1b, w2b, w3b);
    #pragma unroll
    for (int jj = 0; jj < 4; ++jj) {
      const int k = t + (jj << 9);
      const int ak = k ^ mask3;
      const int m = (DI - k) & (DI - 1);
      const int am = m ^ ((m >> 4) & 15);
      float2 Zk = Z[ak], Zm = Z[am];
      Z[ak] = make_float2(0.f, 0.f);
      Z[am] = make_float2(0.f, 0.f);
      float2 E = make_float2(0.5f * (Zk.x + Zm.x), 0.5f * (Zk.y - Zm.y));
      float2 O = make_float2(0.5f * (Zk.y + Zm.y), -0.5f * (Zk.x - Zm.x));
      float2 P = cmul(E, O);          // P2(n)
      carry[jj] = P;
      acc2[jj].x += P.x;
      acc2[jj].y += P.y;
    }
    if (t == 0) {
      float2 Zq = Z[2048];
      Z[2048] = make_float2(0.f, 0.f);
      carryx = Zq.x * Zq.y;
      acc2x += carryx;
    }
    __syncthreads();

    // ---- FFT2: sk2(n) + i*sk0(n+1) ----
    atomicAdd(&Zf[2 * (q2 & 0xFFF)], sgn(xv0, q2));
    atomicAdd(&Zf[2 * (q0 & 0xFFF) + 1], sgn(xv1, q0));
    fft_stages8(Z, t, w1b, w2b, w3b);
    #pragma unroll
    for (int jj = 0; jj < 4; ++jj) {
      const int k = t + (jj << 9);
      const int ak = k ^ mask3;
      const int m = (DI - k) & (DI - 1);
      const int am = m ^ ((m >> 4) & 15);
      float2 Zk = Z[ak], Zm = Z[am];
      Z[ak] = make_float2(0.f, 0.f);
      Z[am] = make_float2(0.f, 0.f);
      float2 E = make_float2(0.5f * (Zk.x + Zm.x), 0.5f * (Zk.y - Zm.y));  // X2(n)
      float2 O = make_float2(0.5f * (Zk.y + Zm.y), -0.5f * (Zk.x - Zm.x)); // X0(n+1)
      float2 P3 = cmul(carry[jj], E);
      acc3[jj].x += P3.x;
      acc3[jj].y += P3.y;
      carry[jj] = O;
    }
    if (t == 0) {
      float2 Zq = Z[2048];
      Z[2048] = make_float2(0.f, 0.f);
      acc3x += carryx * Zq.x;
      carryx = Zq.y;
    }
    __syncthreads();

    // ---- FFT3: sk1(n+1) + i*sk2(n+1) ----
    atomicAdd(&Zf[2 * (q1 & 0xFFF)], sgn(xv1, q1));
    atomicAdd(&Zf[2 * (q2 & 0xFFF) + 1], sgn(xv1, q2));
    fft_stages8(Z, t, w1b, w2b, w3b);
    #pragma unroll
    for (int jj = 0; jj < 4; ++jj) {
      const int k = t + (jj << 9);
      const int ak = k ^ mask3;
      const int m = (DI - k) & (DI - 1);
      const int am = m ^ ((m >> 4) & 15);
      float2 Zk = Z[ak], Zm = Z[am];
      Z[ak] = make_float2(0.f, 0.f);
      Z[am] = make_float2(0.f, 0.f);
      float2 E = make_float2(0.5f * (Zk.x + Zm.x), 0.5f * (Zk.y - Zm.y));  // X1(n+1)
      float2 O = make_float2(0.5f * (Zk.y + Zm.y), -0.5f * (Zk.x - Zm.x)); // X2(n+1)
      float2 P = cmul(carry[jj], E);  // P2(n+1)
      acc2[jj].x += P.x;
      acc2[jj].y += P.y;
      float2 P3 = cmul(P, O);
      acc3[jj].x += P3.x;
      acc3[jj].y += P3.y;
    }
    if (t == 0) {
      float2 Zq = Z[2048];
      Z[2048] = make_float2(0.f, 0.f);
      float tt = carryx * Zq.x;
      acc2x += tt;
      acc3x += tt * Zq.y;
    }
    __syncthreads();
  }

  // ---- writeback ----
  float* S = ws;
  #pragma unroll
  for (int jj = 0; jj < 4; ++jj) {
    const int k = t + (jj << 9);
    float* p2p = S + ((size_t)(bb * 2 + 0) * 2049 + k) * 2;
    atomicAdd(p2p, acc2[jj].x);
    atomicAdd(p2p + 1, acc2[jj].y);
    float* p3p = S + ((size_t)(bb * 2 + 1) * 2049 + k) * 2;
    atomicAdd(p3p, acc3[jj].x);
    atomicAdd(p3p + 1, acc3[jj].y);
  }
  if (t == 0) {
    atomicAdd(S + ((size_t)(bb * 2 + 0) * 2049 + 2048) * 2, acc2x);
    atomicAdd(S + ((size_t)(bb * 2 + 1) * 2049 + 2048) * 2, acc3x);
  }

  const float sc1 = alpha[1] * (1.0f / (float)NPOS);
  float* phi = ws + PHI_OFF;
  atomicAdd(&phi[(size_t)bb * PHI_LEN + 1 + t], xs * sc1);
}

// ---------------- stage 2 (radix-2 FFT, 16 blocks, negligible) -------------
__device__ inline void fft4096_r2(float2* Z, const float2* W, int tid) {
  for (int s = 1; s <= 12; ++s) {
    __syncthreads();
    const int half = 1 << (s - 1);
    const int tsh = 12 - s;
    #pragma unroll
    for (int q = 0; q < 8; ++q) {
      int bidx = tid + q * 256;
      int j = bidx & (half - 1);
      int i1 = ((bidx >> (s - 1)) << s) + j;
      int i2 = i1 + half;
      float2 w = W[j << tsh];
      float2 u = Z[i1];
      float2 v = Z[i2];
      float2 t = cmul(w, v);
      Z[i1] = make_float2(u.x + t.x, u.y + t.y);
      Z[i2] = make_float2(u.x - t.x, u.y - t.y);
    }
  }
  __syncthreads();
}

__global__ __launch_bounds__(256) void cbp_stage2(
    const float* __restrict__ ws_in, const float* __restrict__ alpha,
    float* __restrict__ ws_phi) {
  __shared__ float2 Z[DI];
  __shared__ float2 W[DI / 2];
  const int tid = threadIdx.x;

  for (int r = tid; r < DI / 2; r += 256) {
    float ang = 1.5339807878856412e-3f * (float)r;  // +2pi/4096*r (inverse)
    float sv, cv;
    sincosf(ang, &sv, &cv);
    W[r] = make_float2(cv, sv);
  }

  const int b = blockIdx.x >> 1;
  const int t = blockIdx.x & 1;
  const float* Sp = ws_in + (size_t)(b * 2 + t) * 2049 * 2;

  for (int k = tid; k <= 2048; k += 256) {
    float re = Sp[k * 2];
    float im = Sp[k * 2 + 1];
    Z[__brev((unsigned)k) >> 20] = make_float2(re, im);
    if (k > 0 && k < 2048) {
      Z[__brev((unsigned)(DI - k)) >> 20] = make_float2(re, -im);
    }
  }
  fft4096_r2(Z, W, tid);

  const float scale = alpha[2 + t] / ((float)DI * (float)NPOS);
  float* out = ws_phi + (size_t)b * PHI_LEN + 513 + t * DI;
  for (int d = tid; d < DI; d += 256) out[d] = Z[d].x * scale;
}

__global__ __launch_bounds__(256) void cbp_stage3(
    const float* __restrict__ ws_phi, const float* __restrict__ alpha,
    float* __restrict__ out) {
  __shared__ float red[4];
  const int b = blockIdx.x;
  const int tid = threadIdx.x;
  const float* pr = ws_phi + (size_t)b * PHI_LEN;
  const float a0 = alpha[0];

  float w[35];
  float ssum = 0.f;
  #pragma unroll
  for (int j = 0; j < 35; ++j) {
    const int idx = tid + j * 256;
    float wv = 0.f;
    if (idx < PHI_LEN) {
      float v = (idx == 0) ? a0 : pr[idx];
      float sq = sqrtf(fabsf(v) + 1e-12f);
      wv = (v > 0.f) ? sq : ((v < 0.f) ? -sq : 0.f);
    }
    w[j] = wv;
    ssum += wv * wv;
  }
  for (int off = 32; off > 0; off >>= 1) ssum += __shfl_down(ssum, off);
  if ((tid & 63) == 0) red[tid >> 6] = ssum;
  __syncthreads();
  const float tot = red[0] + red[1] + red[2] + red[3];
  const float inv = 1.0f / sqrtf(tot);

  #pragma unroll
  for (int j = 0; j < 35; ++j) {
    const int idx = tid + j * 256;
    if (idx < PHI_LEN) out[(size_t)b * PHI_LEN + idx] = w[j] * inv;
  }
}

extern "C" void kernel_launch(void* const* d_in, const int* in_sizes, int n_in,
                              void* d_out, int out_size, void* d_ws,
                              size_t ws_size, hipStream_t stream) {
  const float* x = (const float*)d_in[0];
  const float* alpha = (const float*)d_in[1];
  const int* h_idx = (const int*)d_in[2];
  const int* s_bits = (const int*)d_in[3];
  float* out = (float*)d_out;
  float* ws = (float*)d_ws;

  const size_t zero_bytes = (size_t)(S_FLOATS + BATCH * PHI_LEN) * sizeof(float);
  hipMemsetAsync(d_ws, 0, zero_bytes, stream);

  cbp_stage1<<<dim3(BATCH * CHUNKS), dim3(512), 0, stream>>>(x, alpha, h_idx,
                                                             s_bits, ws);
  cbp_stage2<<<dim3(BATCH * 2), dim3(256), 0, stream>>>(ws, alpha,
                                                        ws + PHI_OFF);
  cbp_stage3<<<dim3(BATCH), dim3(256), 0, stream>>>(ws + PHI_OFF, alpha, out);
}